// Round 1
// baseline (92.293 us; speedup 1.0000x reference)
//
#include <hip/hip_runtime.h>

#define T_UTT 50
#define H_DIM 512
#define B_DIM 4096
#define NWAVES 4
#define NT_PW 13   // ceil(T_UTT / NWAVES)

__device__ __forceinline__ float dot8(const float4& a0, const float4& a1,
                                      const float4& b0, const float4& b1) {
    return a0.x * b0.x + a0.y * b0.y + a0.z * b0.z + a0.w * b0.w +
           a1.x * b1.x + a1.y * b1.y + a1.z * b1.z + a1.w * b1.w;
}

__global__ __launch_bounds__(256) void wseq_attn(const float* __restrict__ Q,
                                                 const float* __restrict__ U,
                                                 float* __restrict__ Out) {
    const int b    = blockIdx.x;
    const int tid  = threadIdx.x;
    const int lane = tid & 63;
    const int wave = tid >> 6;
    const int h0   = lane << 3;   // 8 floats per lane, 64 lanes = 512 = H_DIM

    __shared__ float s_dot[T_UTT];
    __shared__ float s_n2[T_UTT];
    __shared__ float s_score[T_UTT];
    __shared__ float s_part[NWAVES][H_DIM];

    // ---- query fragment (each wave holds full q across its 64 lanes) ----
    const float* qb = Q + (size_t)b * H_DIM + h0;
    float4 q0 = *reinterpret_cast<const float4*>(qb);
    float4 q1 = *reinterpret_cast<const float4*>(qb + 4);

    // ---- Phase A: issue ALL utterance loads for this wave's t's ----
    float4 u0[NT_PW], u1[NT_PW];
#pragma unroll
    for (int i = 0; i < NT_PW; ++i) {
        const int t = wave + NWAVES * i;
        if (t < T_UTT) {
            const float* up = U + ((size_t)t * B_DIM + b) * H_DIM + h0;
            u0[i] = *reinterpret_cast<const float4*>(up);
            u1[i] = *reinterpret_cast<const float4*>(up + 4);
        } else {
            u0[i] = make_float4(0.f, 0.f, 0.f, 0.f);
            u1[i] = make_float4(0.f, 0.f, 0.f, 0.f);
        }
    }

    // ---- q norm^2: per-wave butterfly (result in all lanes) ----
    float qn = dot8(q0, q1, q0, q1);
#pragma unroll
    for (int m = 32; m; m >>= 1) qn += __shfl_xor(qn, m, 64);

    // ---- Phase B: dot(q,u_t) and ||u_t||^2, wave-reduced, to LDS ----
#pragma unroll
    for (int i = 0; i < NT_PW; ++i) {
        const int t = wave + NWAVES * i;
        if (t < T_UTT) {
            float d = dot8(q0, q1, u0[i], u1[i]);
            float n = dot8(u0[i], u1[i], u0[i], u1[i]);
#pragma unroll
            for (int m = 32; m; m >>= 1) {
                d += __shfl_xor(d, m, 64);
                n += __shfl_xor(n, m, 64);
            }
            if (lane == 0) { s_dot[t] = d; s_n2[t] = n; }
        }
    }
    __syncthreads();

    // ---- Phase C: scores + softmax (redundant per thread, LDS broadcast) ----
    const float q_inv = rsqrtf(qn);
    if (tid < T_UTT) {
        s_score[tid] = s_dot[tid] * q_inv * rsqrtf(s_n2[tid]);
    }
    __syncthreads();

    float mx = 1.0f;  // the appended fixed score
#pragma unroll
    for (int t = 0; t < T_UTT; ++t) mx = fmaxf(mx, s_score[t]);
    float denom = __expf(1.0f - mx);
#pragma unroll
    for (int t = 0; t < T_UTT; ++t) denom += __expf(s_score[t] - mx);
    const float inv_denom = 1.0f / denom;

    // ---- Phase D: weighted sum from registers ----
    float acc[8] = {0.f, 0.f, 0.f, 0.f, 0.f, 0.f, 0.f, 0.f};
#pragma unroll
    for (int i = 0; i < NT_PW; ++i) {
        const int t = wave + NWAVES * i;
        if (t < T_UTT) {
            const float w = __expf(s_score[t] - mx) * inv_denom;
            acc[0] += w * u0[i].x; acc[1] += w * u0[i].y;
            acc[2] += w * u0[i].z; acc[3] += w * u0[i].w;
            acc[4] += w * u1[i].x; acc[5] += w * u1[i].y;
            acc[6] += w * u1[i].z; acc[7] += w * u1[i].w;
        }
    }
    float4* sp = reinterpret_cast<float4*>(&s_part[wave][h0]);
    sp[0] = make_float4(acc[0], acc[1], acc[2], acc[3]);
    sp[1] = make_float4(acc[4], acc[5], acc[6], acc[7]);
    __syncthreads();

    // ---- cross-wave combine + query term; wave 0 stores ----
    if (wave == 0) {
        const float wq = __expf(1.0f - mx) * inv_denom;
        float o[8];
#pragma unroll
        for (int j = 0; j < 8; ++j) {
            o[j] = s_part[0][h0 + j] + s_part[1][h0 + j] +
                   s_part[2][h0 + j] + s_part[3][h0 + j];
        }
        o[0] += wq * q0.x; o[1] += wq * q0.y; o[2] += wq * q0.z; o[3] += wq * q0.w;
        o[4] += wq * q1.x; o[5] += wq * q1.y; o[6] += wq * q1.z; o[7] += wq * q1.w;
        float* ob = Out + (size_t)b * H_DIM + h0;
        *reinterpret_cast<float4*>(ob)     = make_float4(o[0], o[1], o[2], o[3]);
        *reinterpret_cast<float4*>(ob + 4) = make_float4(o[4], o[5], o[6], o[7]);
    }
}

extern "C" void kernel_launch(void* const* d_in, const int* in_sizes, int n_in,
                              void* d_out, int out_size, void* d_ws, size_t ws_size,
                              hipStream_t stream) {
    const float* Q = (const float*)d_in[0];   // [B, H]
    const float* U = (const float*)d_in[1];   // [T, B, H]
    float* Out = (float*)d_out;               // [B, H]
    wseq_attn<<<dim3(B_DIM), dim3(256), 0, stream>>>(Q, U, Out);
}

// Round 2
// 89.479 us; speedup vs baseline: 1.0314x; 1.0314x over previous
//
#include <hip/hip_runtime.h>

#define T_UTT 50
#define H_DIM 512
#define B_DIM 4096
#define NWAVES 8
#define NT_PW 7    // ceil(T_UTT / NWAVES); waves 0-1 get 7 t's, waves 2-7 get 6

__device__ __forceinline__ float dot8(const float4& a0, const float4& a1,
                                      const float4& b0, const float4& b1) {
    return a0.x * b0.x + a0.y * b0.y + a0.z * b0.z + a0.w * b0.w +
           a1.x * b1.x + a1.y * b1.y + a1.z * b1.z + a1.w * b1.w;
}

// 512 threads = 8 waves per block, one block per batch row b.
// __launch_bounds__(512, 4): 4 waves/EU -> 16 waves/CU -> 2 blocks/CU,
// caps VGPR at 128 (u-array is 56 VGPRs, total ~110 -> no spill expected).
__global__ __launch_bounds__(512, 4) void wseq_attn(const float* __restrict__ Q,
                                                    const float* __restrict__ U,
                                                    float* __restrict__ Out) {
    const int b    = blockIdx.x;
    const int tid  = threadIdx.x;
    const int lane = tid & 63;
    const int wave = tid >> 6;
    const int h0   = lane << 3;   // 8 floats per lane, 64 lanes = 512 = H_DIM

    __shared__ float s_dot[T_UTT];
    __shared__ float s_n2[T_UTT];
    __shared__ float s_score[T_UTT];
    __shared__ float s_q[H_DIM];
    __shared__ float s_part[NWAVES][H_DIM];

    // ---- query fragment (every wave holds full q across its 64 lanes) ----
    const float* qb = Q + (size_t)b * H_DIM + h0;
    float4 q0 = *reinterpret_cast<const float4*>(qb);
    float4 q1 = *reinterpret_cast<const float4*>(qb + 4);
    if (wave == 0) {   // stash q for the fully-parallel epilogue
        *reinterpret_cast<float4*>(&s_q[h0])     = q0;
        *reinterpret_cast<float4*>(&s_q[h0 + 4]) = q1;
    }

    // ---- Phase A: issue ALL utterance loads for this wave's t's ----
    // (compiler pipelines these against Phase B via descending vmcnt waits)
    float4 u0[NT_PW], u1[NT_PW];
#pragma unroll
    for (int i = 0; i < NT_PW; ++i) {
        const int t = wave + NWAVES * i;
        if (t < T_UTT) {
            const float* up = U + ((size_t)t * B_DIM + b) * H_DIM + h0;
            u0[i] = *reinterpret_cast<const float4*>(up);
            u1[i] = *reinterpret_cast<const float4*>(up + 4);
        }
    }

    // ---- q norm^2: per-wave butterfly (result in all lanes) ----
    float qn = dot8(q0, q1, q0, q1);
#pragma unroll
    for (int m = 32; m; m >>= 1) qn += __shfl_xor(qn, m, 64);

    // ---- Phase B: dot(q,u_t) and ||u_t||^2, wave-reduced, to LDS ----
#pragma unroll
    for (int i = 0; i < NT_PW; ++i) {
        const int t = wave + NWAVES * i;
        if (t < T_UTT) {
            float d = dot8(q0, q1, u0[i], u1[i]);
            float n = dot8(u0[i], u1[i], u0[i], u1[i]);
#pragma unroll
            for (int m = 32; m; m >>= 1) {
                d += __shfl_xor(d, m, 64);
                n += __shfl_xor(n, m, 64);
            }
            if (lane == 0) { s_dot[t] = d; s_n2[t] = n; }
        }
    }
    __syncthreads();

    // ---- Phase C: cosine scores (threads 0..49 == wave 0, which has qn) ----
    if (tid < T_UTT) {
        s_score[tid] = s_dot[tid] * rsqrtf(qn) * rsqrtf(s_n2[tid]);
    }
    __syncthreads();

    // softmax over 51 scores, redundant per thread (LDS broadcast reads)
    float mx = 1.0f;  // the appended fixed score for the query itself
#pragma unroll
    for (int t = 0; t < T_UTT; ++t) mx = fmaxf(mx, s_score[t]);
    float denom = __expf(1.0f - mx);
#pragma unroll
    for (int t = 0; t < T_UTT; ++t) denom += __expf(s_score[t] - mx);
    const float inv_denom = 1.0f / denom;

    // ---- Phase D: weighted sum from registers ----
    float acc[8] = {0.f, 0.f, 0.f, 0.f, 0.f, 0.f, 0.f, 0.f};
#pragma unroll
    for (int i = 0; i < NT_PW; ++i) {
        const int t = wave + NWAVES * i;
        if (t < T_UTT) {
            const float w = __expf(s_score[t] - mx) * inv_denom;
            acc[0] += w * u0[i].x; acc[1] += w * u0[i].y;
            acc[2] += w * u0[i].z; acc[3] += w * u0[i].w;
            acc[4] += w * u1[i].x; acc[5] += w * u1[i].y;
            acc[6] += w * u1[i].z; acc[7] += w * u1[i].w;
        }
    }
    float4* sp = reinterpret_cast<float4*>(&s_part[wave][h0]);
    sp[0] = make_float4(acc[0], acc[1], acc[2], acc[3]);
    sp[1] = make_float4(acc[4], acc[5], acc[6], acc[7]);
    __syncthreads();

    // ---- epilogue: fully parallel — each of 512 threads owns one h ----
    const float wq = __expf(1.0f - mx) * inv_denom;
    float o = wq * s_q[tid];
#pragma unroll
    for (int w = 0; w < NWAVES; ++w) o += s_part[w][tid];
    Out[(size_t)b * H_DIM + tid] = o;
}

extern "C" void kernel_launch(void* const* d_in, const int* in_sizes, int n_in,
                              void* d_out, int out_size, void* d_ws, size_t ws_size,
                              hipStream_t stream) {
    const float* Q = (const float*)d_in[0];   // [B, H]
    const float* U = (const float*)d_in[1];   // [T, B, H]
    float* Out = (float*)d_out;               // [B, H]
    wseq_attn<<<dim3(B_DIM), dim3(512), 0, stream>>>(Q, U, Out);
}